// Round 1
// baseline (1018.491 us; speedup 1.0000x reference)
//
#include <hip/hip_runtime.h>

// QuantumFeedForward: out = cos^2(relu(x@W1^T + b1)) @ W2^T + b2
// N=65536 tokens, EMBED=2048, FFN=8. All fp32.
//
// Strategy: HBM-bound (1.03 GB traffic, floor ~163 us @6.3 TB/s).
//  - lane = token  -> all weight indices wave-uniform -> scalar (s_load) pipe
//  - x staged through LDS transpose in 64x32 chunks, prefetch next chunk
//  - FFN=8 split as 2 h-accumulators per wave (4 waves) -> no reduction
//  - out transposed through wave-private LDS tile -> coalesced float4 stores

static constexpr int EMBED = 2048;
static constexpr int FFN   = 8;
static constexpr int TPB   = 64;            // tokens per block
static constexpr int CH    = 32;            // embed columns per chunk
static constexpr int NCH   = EMBED / CH;    // 64 chunks
static constexpr int RS    = 36;            // LDS tile row stride (floats), pad vs 32

__global__ __launch_bounds__(256, 4)
void qffn_kernel(const float* __restrict__ x, const float* __restrict__ W1,
                 const float* __restrict__ b1, const float* __restrict__ W2,
                 const float* __restrict__ b2, float* __restrict__ out)
{
    // region [0, 4*TPB*RS): phase1 x_tile (first TPB*RS) / phase2 per-wave out tiles
    // region [4*TPB*RS, +TPB*12): q exchange buffer
    __shared__ float smem[4 * TPB * RS + TPB * 12];
    float* xt = smem;
    float* qb = smem + 4 * TPB * RS;

    const int tid  = threadIdx.x;
    const int lane = tid & 63;
    const int wv   = __builtin_amdgcn_readfirstlane(tid >> 6);  // 0..3, wave-uniform
    const int n0   = blockIdx.x * TPB;

    // staging map: 512 float4s per chunk, 2 per thread
    const int id1  = tid + 256;
    const int row0 = tid >> 3, col0 = (tid & 7) << 2;
    const int row1 = id1 >> 3, col1 = (id1 & 7) << 2;
    const float* xp0 = x + (long)(n0 + row0) * EMBED + col0;
    const float* xp1 = x + (long)(n0 + row1) * EMBED + col1;

    // prefetch chunk 0
    float4 r0 = *(const float4*)(xp0);
    float4 r1 = *(const float4*)(xp1);

    const int f0 = 2 * wv, f1 = f0 + 1;
    const float* w1a = W1 + f0 * EMBED;   // uniform -> scalar loads
    const float* w1b = W1 + f1 * EMBED;

    float h0 = 0.f, h1 = 0.f;

    // ---------------- Phase 1: h[f0], h[f1] for token = lane ----------------
    for (int c = 0; c < NCH; ++c) {
        __syncthreads();                       // previous chunk reads complete
        *(float4*)(xt + row0 * RS + col0) = r0;
        *(float4*)(xt + row1 * RS + col1) = r1;
        if (c + 1 < NCH) {                     // prefetch next chunk (in flight
            r0 = *(const float4*)(xp0 + (c + 1) * CH);   // during compute)
            r1 = *(const float4*)(xp1 + (c + 1) * CH);
        }
        __syncthreads();                       // tile ready

        float xv[CH];
        #pragma unroll
        for (int j = 0; j < CH / 4; ++j) {
            float4 v = *(const float4*)(xt + lane * RS + 4 * j);
            xv[4*j+0] = v.x; xv[4*j+1] = v.y; xv[4*j+2] = v.z; xv[4*j+3] = v.w;
        }
        const int e0 = c * CH;
        #pragma unroll
        for (int j = 0; j < CH; ++j) {
            h0 = fmaf(xv[j], w1a[e0 + j], h0);  // weights: s_load (uniform)
            h1 = fmaf(xv[j], w1b[e0 + j], h1);
        }
    }

    h0 = fmaxf(h0 + b1[f0], 0.f);
    h1 = fmaxf(h1 + b1[f1], 0.f);
    float c0 = __cosf(h0), c1 = __cosf(h1);

    // ---------------- q exchange across waves ----------------
    qb[lane * 12 + f0] = c0 * c0;
    qb[lane * 12 + f1] = c1 * c1;
    __syncthreads();   // also guarantees all x_tile reads done before out tiles reuse it
    float q[FFN];
    #pragma unroll
    for (int f = 0; f < FFN; ++f) q[f] = qb[lane * 12 + f];

    // ---------------- Phase 2: out[token][e] ----------------
    float* ot = smem + wv * (TPB * RS);        // wave-private tile
    for (int cc = 0; cc < NCH / 4; ++cc) {
        const int e0 = (cc * 4 + wv) * CH;     // wave handles chunks c = wv (mod 4)
        float o[CH];
        #pragma unroll
        for (int j = 0; j < CH; ++j) {
            float acc = b2[e0 + j];            // uniform -> s_load
            #pragma unroll
            for (int f = 0; f < FFN; ++f)
                acc = fmaf(q[f], W2[(e0 + j) * FFN + f], acc);  // uniform -> s_load
            o[j] = acc;
        }
        #pragma unroll
        for (int j = 0; j < CH / 4; ++j)
            *(float4*)(ot + lane * RS + 4 * j) =
                make_float4(o[4*j], o[4*j+1], o[4*j+2], o[4*j+3]);
        __syncthreads();                       // order LDS write -> transposed read
        #pragma unroll
        for (int k = 0; k < 8; ++k) {
            const int id  = k * 64 + lane;
            const int row = id >> 3, c4 = (id & 7) << 2;
            float4 v = *(const float4*)(ot + row * RS + c4);
            *(float4*)(out + (long)(n0 + row) * EMBED + e0 + c4) = v;
        }
        __syncthreads();                       // before next overwrite of ot
    }
}

extern "C" void kernel_launch(void* const* d_in, const int* in_sizes, int n_in,
                              void* d_out, int out_size, void* d_ws, size_t ws_size,
                              hipStream_t stream) {
    const float* x  = (const float*)d_in[0];
    const float* W1 = (const float*)d_in[1];
    const float* b1 = (const float*)d_in[2];
    const float* W2 = (const float*)d_in[3];
    const float* b2 = (const float*)d_in[4];
    float* out = (float*)d_out;

    const int ntok = in_sizes[0] / EMBED;      // 65536
    qffn_kernel<<<dim3(ntok / TPB), dim3(256), 0, stream>>>(x, W1, b1, W2, b2, out);
}